// Round 1
// baseline (45231.174 us; speedup 1.0000x reference)
//
#include <hip/hip_runtime.h>
#include <hip/hip_cooperative_groups.h>
#include <cmath>

namespace cg = cooperative_groups;

// Problem constants (fixed by setup_inputs)
constexpr int B = 32, S = 1024, I = 512, H = 1024;
constexpr float DT = 0.05f;

// ---------------------------------------------------------------------------
// Phase 1: h_in_all[M=B*S][H] = x[M][I] @ W_in[I][H], fp32, written into the
// `outs` region of d_out (the scan consumes/overwrites it in place).
// 64x64 tile, BK=16, 256 threads, 4x4 micro-tile. A staged transposed in LDS.
// ---------------------------------------------------------------------------
__global__ __launch_bounds__(256) void gemm_in(const float* __restrict__ A,
                                               const float* __restrict__ Bw,
                                               float* __restrict__ C) {
    const int bx = blockIdx.x;
    const int nb = bx & 15;       // 1024/64 = 16 col tiles
    const int mb = bx >> 4;       // 32768/64 = 512 row tiles
    const int t  = threadIdx.x;
    const int tx = t & 15, ty = t >> 4;

    __shared__ __align__(16) float As[16][68];  // [k][m], +4 pad
    __shared__ __align__(16) float Bs[16][68];  // [k][n], +4 pad

    float acc[4][4] = {};
    const int row0 = mb * 64, col0 = nb * 64;

    for (int kt = 0; kt < I; kt += 16) {
        // stage A: 64 rows x 16 k (transpose into As[k][m])
        {
            const int m  = t >> 2;
            const int kq = (t & 3) * 4;
            const float4 a = *(const float4*)(A + (size_t)(row0 + m) * I + kt + kq);
            As[kq + 0][m] = a.x; As[kq + 1][m] = a.y;
            As[kq + 2][m] = a.z; As[kq + 3][m] = a.w;
            // stage B: 16 k x 64 n
            const int kk = t >> 4;
            const int n4 = (t & 15) * 4;
            *(float4*)&Bs[kk][n4] =
                *(const float4*)(Bw + (size_t)(kt + kk) * H + col0 + n4);
        }
        __syncthreads();
#pragma unroll
        for (int kk = 0; kk < 16; ++kk) {
            const float4 av = *(const float4*)&As[kk][ty * 4];
            const float4 bv = *(const float4*)&Bs[kk][tx * 4];
            const float ar[4] = {av.x, av.y, av.z, av.w};
            const float br[4] = {bv.x, bv.y, bv.z, bv.w};
#pragma unroll
            for (int i = 0; i < 4; ++i)
#pragma unroll
                for (int j = 0; j < 4; ++j) acc[i][j] += ar[i] * br[j];
        }
        __syncthreads();
    }
#pragma unroll
    for (int i = 0; i < 4; ++i) {
        float4 v = make_float4(acc[i][0], acc[i][1], acc[i][2], acc[i][3]);
        *(float4*)(C + (size_t)(row0 + ty * 4 + i) * H + col0 + tx * 4) = v;
    }
}

// ---------------------------------------------------------------------------
// Phase 2: sequential scan, cooperative launch, 256 blocks x 256 threads,
// 1 block/CU (148 KB LDS). Block owns 4 output columns c0..c0+3.
// Per step: stage full h_prev (= out[:, s-1, :]) into LDS (coalesced),
// each (b,u) output computed by 2 threads splitting K=1024 in half.
// State lives in d_out itself: out[b][s][:] is h_in before, h_s after.
// ---------------------------------------------------------------------------
__global__ __launch_bounds__(256) void scan_k(const float* __restrict__ Wrec,
                                              const float* __restrict__ bias,
                                              const float* __restrict__ tau,
                                              float* __restrict__ out) {
    cg::grid_group grid = cg::this_grid();
    const int t  = threadIdx.x;
    const int c0 = blockIdx.x * 4;

    // padded rows (1028): float4 reads land on distinct-or-2-way banks (free)
    __shared__ __align__(16) float h_lds[32 * 1028];  // 131,584 B
    __shared__ __align__(16) float w_lds[4 * 1028];   //  16,448 B
    __shared__ float part[128];                       //     512 B
    __shared__ float ab[8];                           // alpha[4], bias[4]

    // one-time: W_rec column slice -> LDS, w_lds[u][k] = Wrec[k][c0+u]
    for (int p = 0; p < 16; ++p) {
        const int k = p * 64 + (t >> 2);
        const int u = t & 3;
        w_lds[u * 1028 + k] = Wrec[(size_t)k * H + c0 + u];
    }
    if (t < 4) {
        ab[t]     = expf(-DT / tau[c0 + t]);  // alpha
        ab[4 + t] = bias[c0 + t];
    }
    // (first __syncthreads below covers w_lds/ab visibility)

    const int kh = t >> 7;         // K-half: 0 or 1
    const int b  = (t >> 2) & 31;  // batch row
    const int u  = t & 3;          // column within slice
    const int c  = c0 + u;
    float hlast = 0.f;

    for (int s = 0; s < S; ++s) {
        // ---- stage h_prev into LDS (32*1024 floats, coalesced float4) ----
        if (s == 0) {
            const float4 z4 = make_float4(0.f, 0.f, 0.f, 0.f);
            for (int j = t; j < 8192; j += 256) {
                const int flat = j * 4;
                *(float4*)&h_lds[(flat >> 10) * 1028 + (flat & 1023)] = z4;
            }
        } else {
            for (int j = t; j < 8192; j += 256) {
                const int flat = j * 4;
                const int bb = flat >> 10, k = flat & 1023;
                const float4 v = *(const float4*)(out + (size_t)bb * S * H +
                                                  (size_t)(s - 1) * H + k);
                *(float4*)&h_lds[bb * 1028 + k] = v;
            }
        }
        __syncthreads();

        // ---- partial dot over this thread's K-half (4 indep. acc chains) --
        float a0 = 0.f, a1 = 0.f, a2 = 0.f, a3 = 0.f;
        const float* hrow = h_lds + b * 1028 + kh * 512;
        const float* wrow = w_lds + u * 1028 + kh * 512;
#pragma unroll 8
        for (int k = 0; k < 512; k += 4) {
            const float4 hv = *(const float4*)(hrow + k);
            const float4 wv = *(const float4*)(wrow + k);
            a0 += hv.x * wv.x; a1 += hv.y * wv.y;
            a2 += hv.z * wv.z; a3 += hv.w * wv.w;
        }
        float acc = (a0 + a1) + (a2 + a3);
        if (kh == 1) part[b * 4 + u] = acc;
        __syncthreads();

        if (kh == 0) {
            acc += part[b * 4 + u];
            const size_t oidx = (size_t)b * S * H + (size_t)s * H + c;
            const float z     = out[oidx] + acc + ab[4 + u];  // h_in + rec + bias
            const float ht    = tanhf(z);
            const float al    = ab[u];
            const float hprev = h_lds[b * 1028 + c];
            const float hn    = al * hprev + (1.f - al) * ht;
            out[oidx] = hn;
            hlast = hn;
        }
        grid.sync();  // publish h_s before anyone stages step s+1
    }

    if (kh == 0) {
        // h_last tail region after the outs block
        out[(size_t)B * S * H + (size_t)b * H + c] = hlast;
    }
}

// ---------------------------------------------------------------------------
extern "C" void kernel_launch(void* const* d_in, const int* in_sizes, int n_in,
                              void* d_out, int out_size, void* d_ws, size_t ws_size,
                              hipStream_t stream) {
    (void)in_sizes; (void)n_in; (void)out_size; (void)d_ws; (void)ws_size;
    const float* x    = (const float*)d_in[0];
    const float* W_in = (const float*)d_in[1];
    const float* Wrec = (const float*)d_in[2];
    const float* bs   = (const float*)d_in[3];
    const float* tu   = (const float*)d_in[4];
    float* outp = (float*)d_out;

    // Phase 1: input projection into the outs region of d_out
    gemm_in<<<dim3(512 * 16), dim3(256), 0, stream>>>(x, W_in, outp);

    // Phase 2: cooperative scan (grid.sync per timestep)
    void* kargs[4] = {(void*)&Wrec, (void*)&bs, (void*)&tu, (void*)&outp};
    hipLaunchCooperativeKernel((void*)scan_k, dim3(256), dim3(256), kargs, 0,
                               stream);
}

// Round 3
// 21527.161 us; speedup vs baseline: 2.1011x; 2.1011x over previous
//
#include <hip/hip_runtime.h>
#include <cmath>

// Problem constants (fixed by setup_inputs)
constexpr int B = 32, S = 1024, I = 512, H = 1024;
constexpr float DT = 0.05f;

// ---------------------------------------------------------------------------
// Phase 1: h_in_all[M=B*S][H] = x[M][I] @ W_in[I][H], fp32, written into the
// `outs` region of d_out (the scan consumes/overwrites it in place).
// 64x64 tile, BK=16, 256 threads, 4x4 micro-tile. (unchanged from R1, passed)
// ---------------------------------------------------------------------------
__global__ __launch_bounds__(256) void gemm_in(const float* __restrict__ A,
                                               const float* __restrict__ Bw,
                                               float* __restrict__ C) {
    const int bx = blockIdx.x;
    const int nb = bx & 15;       // 1024/64 = 16 col tiles
    const int mb = bx >> 4;       // 32768/64 = 512 row tiles
    const int t  = threadIdx.x;
    const int tx = t & 15, ty = t >> 4;

    __shared__ __align__(16) float As[16][68];
    __shared__ __align__(16) float Bs[16][68];

    float acc[4][4] = {};
    const int row0 = mb * 64, col0 = nb * 64;

    for (int kt = 0; kt < I; kt += 16) {
        {
            const int m  = t >> 2;
            const int kq = (t & 3) * 4;
            const float4 a = *(const float4*)(A + (size_t)(row0 + m) * I + kt + kq);
            As[kq + 0][m] = a.x; As[kq + 1][m] = a.y;
            As[kq + 2][m] = a.z; As[kq + 3][m] = a.w;
            const int kk = t >> 4;
            const int n4 = (t & 15) * 4;
            *(float4*)&Bs[kk][n4] =
                *(const float4*)(Bw + (size_t)(kt + kk) * H + col0 + n4);
        }
        __syncthreads();
#pragma unroll
        for (int kk = 0; kk < 16; ++kk) {
            const float4 av = *(const float4*)&As[kk][ty * 4];
            const float4 bv = *(const float4*)&Bs[kk][tx * 4];
            const float ar[4] = {av.x, av.y, av.z, av.w};
            const float br[4] = {bv.x, bv.y, bv.z, bv.w};
#pragma unroll
            for (int i = 0; i < 4; ++i)
#pragma unroll
                for (int j = 0; j < 4; ++j) acc[i][j] += ar[i] * br[j];
        }
        __syncthreads();
    }
#pragma unroll
    for (int i = 0; i < 4; ++i) {
        float4 v = make_float4(acc[i][0], acc[i][1], acc[i][2], acc[i][3]);
        *(float4*)(C + (size_t)(row0 + ty * 4 + i) * H + col0 + tx * 4) = v;
    }
}

// ---------------------------------------------------------------------------
// 2-level tree barrier: 16 groups x 16 blocks, monotonic epoch counters.
// bws layout (ints, 128B apart): [g*32] 16 L1 ctrs, [16*32] root, [17*32] flag.
// Same agent-scope release/acquire primitives cg::grid.sync uses (R1-proven
// coherence path), but 16-deep contention instead of 256-deep.
// ---------------------------------------------------------------------------
__device__ __forceinline__ void grid_barrier(int* bws, int e, int bid) {
    __syncthreads();   // compiler drains vmcnt(0) before s_barrier => all
                       // block stores are at L2 before tid0's release RMW
    if (threadIdx.x == 0) {
        int* c1   = bws + (bid >> 4) * 32;
        int* root = bws + 16 * 32;
        int* flag = bws + 17 * 32;
        const int old = __hip_atomic_fetch_add(c1, 1, __ATOMIC_ACQ_REL,
                                               __HIP_MEMORY_SCOPE_AGENT);
        if (old == e * 16 + 15) {  // last of my 16-block group this epoch
            const int r = __hip_atomic_fetch_add(root, 1, __ATOMIC_ACQ_REL,
                                                 __HIP_MEMORY_SCOPE_AGENT);
            if (r == e * 16 + 15) {  // last group overall
                __hip_atomic_store(flag, e + 1, __ATOMIC_RELEASE,
                                   __HIP_MEMORY_SCOPE_AGENT);
            }
        }
        while (__hip_atomic_load(flag, __ATOMIC_ACQUIRE,
                                 __HIP_MEMORY_SCOPE_AGENT) <= e) {
            __builtin_amdgcn_s_sleep(1);
        }
    }
    __syncthreads();
}

// fma of scalar s into 4-wide accumulator (function, NOT a macro: a macro
// parameter named `w` would also substitute the .w member token)
__device__ __forceinline__ void fma4(float4& acc, float sc, const float4 wv) {
    acc.x = fmaf(sc, wv.x, acc.x);
    acc.y = fmaf(sc, wv.y, acc.y);
    acc.z = fmaf(sc, wv.z, acc.z);
    acc.w = fmaf(sc, wv.w, acc.w);
}

// ---------------------------------------------------------------------------
// Phase 2 scan. 256 blocks = 8 batch-groups(4 b) x 32 col-groups(32 c).
// W_rec slice lives in REGISTERS (constant across steps): thread (ks,cq)
// holds W[ks*32..+32)[c0+cq*4..+4) as 32 float4.
// h_prev staged per step into LDS in [k][b] layout with a 4-float pad every
// 32 k (addr = k*4 + (k>>5)*4 + b) -> the compute-phase b128 reads hit 8
// distinct bank-quads per wave instr (conflict-free broadcast).
// k-split 32 partials reduced through LDS (reads stride-1, conflict-free).
// ---------------------------------------------------------------------------
__global__ __launch_bounds__(256) void scan_k(const float* __restrict__ Wrec,
                                              const float* __restrict__ bias,
                                              const float* __restrict__ tau,
                                              float* __restrict__ out,
                                              int* __restrict__ bws) {
    const int t   = threadIdx.x;
    const int bid = blockIdx.x;
    const int b0  = (bid >> 5) * 4;   // 4 batches
    const int c0  = (bid & 31) * 32;  // 32 cols

    __shared__ __align__(16) float h_lds[4224];      // [k][b] swizzled, 16.9 KB
    __shared__ __align__(16) float part[32 * 128];   // [ks][out], 16 KB

    // --- one-time: W slice into registers ---
    const int ks = t >> 3;        // 0..31, k-range [ks*32, +32)
    const int cq = t & 7;         // 0..7, col-quad
    const int cc = c0 + cq * 4;
    float4 wreg[32];
#pragma unroll
    for (int kk = 0; kk < 32; ++kk)
        wreg[kk] = *(const float4*)&Wrec[(size_t)(ks * 32 + kk) * H + cc];

    // --- one-time: per-output constants for reduce threads (t<128) ---
    const int br = t >> 5;        // batch within group
    const int jc = t & 31;        // col within group
    const int c  = c0 + jc;
    float al = 0.f, bi = 0.f;
    if (t < 128) { al = __expf(-DT / tau[c]); bi = bias[c]; }

    const float* hb = &h_lds[ks * 132];   // swizzled base for my k-range

    for (int s = 0; s < S; ++s) {
        // ---- stage h_prev (4 rows x 1024) into LDS [k][b] ----
#pragma unroll
        for (int it = 0; it < 4; ++it) {
            const int idx = t + it * 256;
            const int bb  = idx >> 8;       // 0..3
            const int k4  = idx & 255;      // float4 index along k
            const int a   = k4 * 16 + (k4 >> 3) * 4 + bb;
            if (s == 0) {
                h_lds[a] = 0.f; h_lds[a + 4] = 0.f;
                h_lds[a + 8] = 0.f; h_lds[a + 12] = 0.f;
            } else {
                const float4 g = *(const float4*)&out[(size_t)(b0 + bb) * S * H +
                                                      (size_t)(s - 1) * H + k4 * 4];
                h_lds[a] = g.x; h_lds[a + 4] = g.y;
                h_lds[a + 8] = g.z; h_lds[a + 12] = g.w;
            }
        }
        __syncthreads();

        // ---- partials: 4 b x 4 c over my 32 k (1 b128 read -> 16 FMA) ----
        float4 a0 = make_float4(0.f, 0.f, 0.f, 0.f);
        float4 a1 = a0, a2 = a0, a3 = a0;
#pragma unroll
        for (int kk = 0; kk < 32; ++kk) {
            const float4 h4 = *(const float4*)(hb + kk * 4);
            const float4 w4 = wreg[kk];
            fma4(a0, h4.x, w4);
            fma4(a1, h4.y, w4);
            fma4(a2, h4.z, w4);
            fma4(a3, h4.w, w4);
        }
        {
            float* pp = &part[ks * 128 + cq * 4];
            *(float4*)(pp +  0) = a0;
            *(float4*)(pp + 32) = a1;
            *(float4*)(pp + 64) = a2;
            *(float4*)(pp + 96) = a3;
        }
        __syncthreads();

        // ---- reduce k-split, tanh, blend, publish ----
        if (t < 128) {
            float sum = 0.f;
#pragma unroll
            for (int q = 0; q < 32; ++q) sum += part[q * 128 + t];
            const size_t oidx = (size_t)(b0 + br) * S * H + (size_t)s * H + c;
            const float z  = out[oidx] + sum + bi;     // h_in + rec + bias
            const float e2 = __expf(2.f * z);
            const float ht = 1.f - 2.f / (e2 + 1.f);   // tanh(z)
            const float hp = h_lds[c * 4 + (c >> 5) * 4 + br];
            const float hn = al * hp + (1.f - al) * ht;
            out[oidx] = hn;
            if (s == S - 1)
                out[(size_t)B * S * H + (size_t)(b0 + br) * H + c] = hn;
        }
        grid_barrier(bws, s, bid);
    }
}

// ---------------------------------------------------------------------------
extern "C" void kernel_launch(void* const* d_in, const int* in_sizes, int n_in,
                              void* d_out, int out_size, void* d_ws, size_t ws_size,
                              hipStream_t stream) {
    (void)in_sizes; (void)n_in; (void)out_size;
    const float* x    = (const float*)d_in[0];
    const float* W_in = (const float*)d_in[1];
    const float* Wrec = (const float*)d_in[2];
    const float* bs   = (const float*)d_in[3];
    const float* tu   = (const float*)d_in[4];
    float* outp = (float*)d_out;
    int*   bwsp = (int*)d_ws;

    // zero the barrier counters (d_ws is re-poisoned 0xAA before every call)
    size_t zb = 18 * 32 * sizeof(int);
    if (zb > ws_size) zb = ws_size;
    (void)hipMemsetAsync(d_ws, 0, zb, stream);

    // Phase 1: input projection into the outs region of d_out
    gemm_in<<<dim3(512 * 16), dim3(256), 0, stream>>>(x, W_in, outp);

    // Phase 2: cooperative launch (co-residency guarantee), custom barrier
    void* kargs[5] = {(void*)&Wrec, (void*)&bs, (void*)&tu, (void*)&outp,
                      (void*)&bwsp};
    (void)hipLaunchCooperativeKernel((void*)scan_k, dim3(256), dim3(256), kargs,
                                     0, stream);
}

// Round 4
// 9809.292 us; speedup vs baseline: 4.6111x; 2.1946x over previous
//
#include <hip/hip_runtime.h>
#include <cmath>

// Problem constants (fixed by setup_inputs)
constexpr int B = 32, S = 1024, I = 512, H = 1024;
constexpr float DT = 0.05f;

// ---------------------------------------------------------------------------
// Phase 1: h_in_all[M=B*S][H] = x[M][I] @ W_in[I][H], fp32, written into the
// `outs` region of d_out (the scan consumes/overwrites it in place).
// 64x64 tile, BK=16, 256 threads, 4x4 micro-tile. (unchanged, ~0.6 ms)
// ---------------------------------------------------------------------------
__global__ __launch_bounds__(256) void gemm_in(const float* __restrict__ A,
                                               const float* __restrict__ Bw,
                                               float* __restrict__ C) {
    const int bx = blockIdx.x;
    const int nb = bx & 15;       // 1024/64 = 16 col tiles
    const int mb = bx >> 4;       // 32768/64 = 512 row tiles
    const int t  = threadIdx.x;
    const int tx = t & 15, ty = t >> 4;

    __shared__ __align__(16) float As[16][68];
    __shared__ __align__(16) float Bs[16][68];

    float acc[4][4] = {};
    const int row0 = mb * 64, col0 = nb * 64;

    for (int kt = 0; kt < I; kt += 16) {
        {
            const int m  = t >> 2;
            const int kq = (t & 3) * 4;
            const float4 a = *(const float4*)(A + (size_t)(row0 + m) * I + kt + kq);
            As[kq + 0][m] = a.x; As[kq + 1][m] = a.y;
            As[kq + 2][m] = a.z; As[kq + 3][m] = a.w;
            const int kk = t >> 4;
            const int n4 = (t & 15) * 4;
            *(float4*)&Bs[kk][n4] =
                *(const float4*)(Bw + (size_t)(kt + kk) * H + col0 + n4);
        }
        __syncthreads();
#pragma unroll
        for (int kk = 0; kk < 16; ++kk) {
            const float4 av = *(const float4*)&As[kk][ty * 4];
            const float4 bv = *(const float4*)&Bs[kk][tx * 4];
            const float ar[4] = {av.x, av.y, av.z, av.w};
            const float br[4] = {bv.x, bv.y, bv.z, bv.w};
#pragma unroll
            for (int i = 0; i < 4; ++i)
#pragma unroll
                for (int j = 0; j < 4; ++j) acc[i][j] += ar[i] * br[j];
        }
        __syncthreads();
    }
#pragma unroll
    for (int i = 0; i < 4; ++i) {
        float4 v = make_float4(acc[i][0], acc[i][1], acc[i][2], acc[i][3]);
        *(float4*)(C + (size_t)(row0 + ty * 4 + i) * H + col0 + tx * 4) = v;
    }
}

// ---------------------------------------------------------------------------
// Flush-free 2-level tree barrier (16 groups x 16 blocks, epoch counters).
// ALL atomics RELAXED: no buffer_wbl2 / per-poll buffer_inv (the R3 20us/step
// cost). Ordering contract:
//   producer: all cross-block data moves via sc0/sc1 (agent-scope relaxed)
//     stores, which complete AT the device coherence point; the compiler's
//     mandatory s_waitcnt vmcnt(0) before s_barrier (__syncthreads) drains
//     them in every wave before tid0 runs the counter RMW.
//   consumer: one acquire fence per block per step after the poll succeeds.
// ---------------------------------------------------------------------------
__device__ __forceinline__ void grid_barrier(int* bws, int e, int bid) {
    __syncthreads();
    if (threadIdx.x == 0) {
        int* c1   = bws + (bid >> 4) * 32;
        int* root = bws + 16 * 32;
        int* flag = bws + 17 * 32;
        const int old = __hip_atomic_fetch_add(c1, 1, __ATOMIC_RELAXED,
                                               __HIP_MEMORY_SCOPE_AGENT);
        if (old == e * 16 + 15) {  // last of my 16-block group this epoch
            const int r = __hip_atomic_fetch_add(root, 1, __ATOMIC_RELAXED,
                                                 __HIP_MEMORY_SCOPE_AGENT);
            if (r == e * 16 + 15) {  // last group overall
                __hip_atomic_store(flag, e + 1, __ATOMIC_RELAXED,
                                   __HIP_MEMORY_SCOPE_AGENT);
            }
        }
        while (__hip_atomic_load(flag, __ATOMIC_RELAXED,
                                 __HIP_MEMORY_SCOPE_AGENT) <= e) {
            __builtin_amdgcn_s_sleep(2);
        }
        __builtin_amdgcn_fence(__ATOMIC_ACQUIRE, "agent");
    }
    __syncthreads();
}

// fma of scalar into 4-wide accumulator (function, not macro: token-substitution)
__device__ __forceinline__ void fma4(float4& acc, float sc, const float4 wv) {
    acc.x = fmaf(sc, wv.x, acc.x);
    acc.y = fmaf(sc, wv.y, acc.y);
    acc.z = fmaf(sc, wv.z, acc.z);
    acc.w = fmaf(sc, wv.w, acc.w);
}

// ---------------------------------------------------------------------------
// Phase 2 scan. 256 blocks = 8 batch-groups(4 b) x 32 col-groups(32 c).
// W_rec slice in registers (128 VGPR; launch_bounds(256,1) gives 512 budget).
// h state is exchanged THROUGH out[] with agent-scope relaxed atomic
// load/store (sc0/sc1: coherent at device level, bypasses stale L1/L2 —
// replaces R3's reliance on per-barrier full-cache invalidates).
// ---------------------------------------------------------------------------
__global__ __launch_bounds__(256, 1) void scan_k(const float* __restrict__ Wrec,
                                                 const float* __restrict__ bias,
                                                 const float* __restrict__ tau,
                                                 float* __restrict__ out,
                                                 int* __restrict__ bws) {
    const int t   = threadIdx.x;
    const int bid = blockIdx.x;
    const int b0  = (bid >> 5) * 4;   // 4 batches
    const int c0  = (bid & 31) * 32;  // 32 cols

    __shared__ __align__(16) float h_lds[4224];      // [k][b] swizzled, 16.9 KB
    __shared__ __align__(16) float part[32 * 128];   // [ks][out], 16 KB

    // --- one-time: W slice into registers ---
    const int ks = t >> 3;        // 0..31, k-range [ks*32, +32)
    const int cq = t & 7;         // 0..7, col-quad
    const int cc = c0 + cq * 4;
    float4 wreg[32];
#pragma unroll
    for (int kk = 0; kk < 32; ++kk)
        wreg[kk] = *(const float4*)&Wrec[(size_t)(ks * 32 + kk) * H + cc];

    // --- one-time: per-output constants for reduce threads (t<128) ---
    const int br = t >> 5;        // batch within group
    const int jc = t & 31;        // col within group
    const int c  = c0 + jc;
    float al = 0.f, bi = 0.f;
    if (t < 128) { al = __expf(-DT / tau[c]); bi = bias[c]; }
    const size_t obase = (size_t)(b0 + br) * S * H + c;  // + s*H per step

    const float* hb = &h_lds[ks * 132];   // swizzled base for my k-range

    for (int s = 0; s < S; ++s) {
        // ---- early issue: h_in for this step (plain cached load) ----
        float hin = 0.f;
        if (t < 128) hin = out[obase + (size_t)s * H];

        // ---- stage h_prev into LDS [k][b] via coherent (sc1) dword loads --
#pragma unroll
        for (int it = 0; it < 16; ++it) {
            const int idx = t + it * 256;   // 0..4095
            const int k   = idx & 1023;
            const int bb  = idx >> 10;
            const int a   = k * 4 + (k >> 5) * 4 + bb;
            float v = 0.f;
            if (s > 0)
                v = __hip_atomic_load(&out[(size_t)(b0 + bb) * S * H +
                                           (size_t)(s - 1) * H + k],
                                      __ATOMIC_RELAXED,
                                      __HIP_MEMORY_SCOPE_AGENT);
            h_lds[a] = v;
        }
        __syncthreads();

        // ---- partials: 4 b x 4 c over my 32 k (1 b128 read -> 16 FMA) ----
        float4 a0 = make_float4(0.f, 0.f, 0.f, 0.f);
        float4 a1 = a0, a2 = a0, a3 = a0;
#pragma unroll
        for (int kk = 0; kk < 32; ++kk) {
            const float4 h4 = *(const float4*)(hb + kk * 4);
            const float4 w4 = wreg[kk];
            fma4(a0, h4.x, w4);
            fma4(a1, h4.y, w4);
            fma4(a2, h4.z, w4);
            fma4(a3, h4.w, w4);
        }
        {
            float* pp = &part[ks * 128 + cq * 4];
            *(float4*)(pp +  0) = a0;
            *(float4*)(pp + 32) = a1;
            *(float4*)(pp + 64) = a2;
            *(float4*)(pp + 96) = a3;
        }
        __syncthreads();

        // ---- reduce k-split, tanh, blend, publish via coherent store ----
        if (t < 128) {
            float sum = 0.f;
#pragma unroll
            for (int q = 0; q < 32; ++q) sum += part[q * 128 + t];
            const float z  = hin + sum + bi;           // h_in + rec + bias
            const float e2 = __expf(2.f * z);
            const float ht = 1.f - 2.f / (e2 + 1.f);   // tanh(z)
            const float hp = h_lds[c * 4 + (c >> 5) * 4 + br];
            const float hn = al * hp + (1.f - al) * ht;
            __hip_atomic_store(&out[obase + (size_t)s * H], hn,
                               __ATOMIC_RELAXED, __HIP_MEMORY_SCOPE_AGENT);
            if (s == S - 1)
                out[(size_t)B * S * H + (size_t)(b0 + br) * H + c] = hn;
        }
        grid_barrier(bws, s, bid);
    }
}

// ---------------------------------------------------------------------------
extern "C" void kernel_launch(void* const* d_in, const int* in_sizes, int n_in,
                              void* d_out, int out_size, void* d_ws, size_t ws_size,
                              hipStream_t stream) {
    (void)in_sizes; (void)n_in; (void)out_size;
    const float* x    = (const float*)d_in[0];
    const float* W_in = (const float*)d_in[1];
    const float* Wrec = (const float*)d_in[2];
    const float* bs   = (const float*)d_in[3];
    const float* tu   = (const float*)d_in[4];
    float* outp = (float*)d_out;
    int*   bwsp = (int*)d_ws;

    // zero the barrier counters (d_ws is re-poisoned 0xAA before every call)
    size_t zb = 18 * 32 * sizeof(int);
    if (zb > ws_size) zb = ws_size;
    (void)hipMemsetAsync(d_ws, 0, zb, stream);

    // Phase 1: input projection into the outs region of d_out
    gemm_in<<<dim3(512 * 16), dim3(256), 0, stream>>>(x, W_in, outp);

    // Phase 2: cooperative launch (co-residency guarantee), custom barrier
    void* kargs[5] = {(void*)&Wrec, (void*)&bs, (void*)&tu, (void*)&outp,
                      (void*)&bwsp};
    (void)hipLaunchCooperativeKernel((void*)scan_k, dim3(256), dim3(256), kargs,
                                     0, stream);
}